// Round 9
// baseline (33781.494 us; speedup 1.0000x reference)
//
#include <hip/hip_runtime.h>
#include <hip/hip_bf16.h>

// FP32-intermediate pipeline; R14: split-bf16 MFMA GEMM.
// R15: hoist t-invariant E-weighted merge out of the t-loop (WM buffers).
// R16/17: premerged kernels: simple stage->barrier->compute (fixed spill).
// R18: dual-n gate fallback (k_gateW2 full-xg, 238->148us, matched).
// R19: gemmM 128x64/BK=64 stride-72 (conflicts 9.4M->3.1M; 7566->6559us).
// R20/21: chunked-xg REGRESSED (in-loop x loads serialized + write amp).
// R22: k_candW2f dual-n cand fallback, full upfront xg (6559->6229us).
// R23: o-split wm staging in the gather fallbacks: per k-chunk do
// {merge o-half -> sync -> dot j-half -> sync} x2. Same gathers, same xg
// (upfront), same per-acc[j] k-order -> bitwise-same. LDS: gate1 70->52KB
// (3 blk/CU), gate0 58->39KB (4), cand 52->43 / 30KB. Attacks the 3.4x
// latency gap above the ~40us L2-gather roofline at 2 blk/CU.

#define B_    16
#define T_    12
#define N_    2048
#define HID_  64
#define ED_   10
#define HOR_  12
#define BH    (B_*HID_)    // 1024
#define BT    (B_*T_)      // 192

typedef __hip_bfloat16 bf16;
typedef __attribute__((ext_vector_type(8))) short short8;
typedef __attribute__((ext_vector_type(4))) float floatx4;

__device__ __forceinline__ float b2f(bf16 x){ return __bfloat162float(x); }
__device__ __forceinline__ bf16  f2b(float x){ return __float2bfloat16(x); }
__device__ __forceinline__ float bits2f(unsigned u) {
  union { float f; unsigned i; } c; c.i = u << 16; return c.f;
}
__device__ __forceinline__ float ldin(const void* p, size_t i, int isbf) {
  return isbf ? b2f(((const bf16*)p)[i]) : ((const float*)p)[i];
}
__device__ __forceinline__ void fma4(float4& a, float s, const float4& b) {
  a.x += s*b.x; a.y += s*b.y; a.z += s*b.z; a.w += s*b.w;
}

// ---------------------------------------------------------------------------
// dtype detector on E (bits 14:7 of 32-bit words: bf16 exponent vs mantissa)
// ---------------------------------------------------------------------------
__global__ void k_detect(const void* __restrict__ E, int* __restrict__ flag) {
  __shared__ int cnt;
  if (threadIdx.x == 0) cnt = 0;
  __syncthreads();
  const unsigned* w = (const unsigned*)E;
  int c = 0;
  for (int i = threadIdx.x; i < 4096; i += 256) {
    const unsigned e = (w[i] >> 7) & 0xFFu;
    if (e >= 0x6Eu && e <= 0x86u) ++c;
  }
  atomicAdd(&cnt, c);
  __syncthreads();
  if (threadIdx.x == 0) flag[0] = (cnt > 2048) ? 1 : 0;
}

// --- input casts to fp32 internal buffers ---
__global__ void k_castE(const void* __restrict__ E, float* __restrict__ Ein,
                        const int* __restrict__ flag) {
  const int i = blockIdx.x*256 + threadIdx.x;
  if (i < N_*ED_) Ein[i] = ldin(E, i, flag[0]);
}
__global__ void k_castsrc(const void* __restrict__ src, float* __restrict__ srcf,
                          const int* __restrict__ flag) {
  const int i = blockIdx.x*256 + threadIdx.x;
  if (i < B_*T_*N_) srcf[i] = ldin(src, i, flag[0]);
}
__global__ void k_castc(const void* __restrict__ cw, const void* __restrict__ cb,
                        float* __restrict__ cwf, float* __restrict__ cbf,
                        const int* __restrict__ flag) {
  const int i = blockIdx.x*256 + threadIdx.x;
  const int f = flag[0];
  if (i < HOR_*HID_) cwf[i] = ldin(cw, i, f);
  if (i < HOR_)      cbf[i] = ldin(cb, i, f);
}

// ---------------------------------------------------------------------------
// S = softmax(relu(Ein @ Ein^T), axis=1) -> fp32 row-major
// ---------------------------------------------------------------------------
__global__ __launch_bounds__(256) void k_softmax_S(const float* __restrict__ Ein,
                                                   float* __restrict__ S) {
  const int n = blockIdx.x, tid = threadIdx.x;
  __shared__ float er[ED_];
  __shared__ float red[4];
  if (tid < ED_) er[tid] = Ein[n*ED_ + tid];
  __syncthreads();
  float e[ED_];
#pragma unroll
  for (int d = 0; d < ED_; ++d) e[d] = er[d];
  float v[8];
  float mx = 0.f;
#pragma unroll
  for (int j = 0; j < 8; ++j) {
    const int m = tid + j*256;
    float dot = 0.f;
#pragma unroll
    for (int d = 0; d < ED_; ++d) dot += e[d]*Ein[m*ED_ + d];
    v[j] = fmaxf(dot, 0.f);
    mx = fmaxf(mx, v[j]);
  }
  for (int o = 32; o; o >>= 1) mx = fmaxf(mx, __shfl_xor(mx, o, 64));
  if ((tid & 63) == 0) red[tid >> 6] = mx;
  __syncthreads();
  mx = fmaxf(fmaxf(red[0], red[1]), fmaxf(red[2], red[3]));
  __syncthreads();
  float sum = 0.f;
#pragma unroll
  for (int j = 0; j < 8; ++j) { v[j] = __expf(v[j] - mx); sum += v[j]; }
  for (int o = 32; o; o >>= 1) sum += __shfl_xor(sum, o, 64);
  if ((tid & 63) == 0) red[tid >> 6] = sum;
  __syncthreads();
  sum = red[0] + red[1] + red[2] + red[3];
  const float inv = 1.f / sum;
#pragma unroll
  for (int j = 0; j < 8; ++j)
    S[(size_t)n*N_ + tid + j*256] = v[j]*inv;
}

// split fp32 -> hi/lo bf16 pair
__global__ void k_splitS(const float* __restrict__ S, bf16* __restrict__ Sh,
                         bf16* __restrict__ Sl, int n) {
  const int i = blockIdx.x*256 + threadIdx.x;
  if (i < n) {
    const float v = S[i];
    const bf16 h = f2b(v);
    Sh[i] = h;
    Sl[i] = f2b(v - b2f(h));
  }
}

// ---------------------------------------------------------------------------
// Basis weights -> PACKED d-interleaved layout, fp32 + bf16 (R13 verbatim).
// ---------------------------------------------------------------------------
template<int LAYER>
__global__ __launch_bounds__(256) void k_prepP(const void* __restrict__ Wb,
                                               float* __restrict__ PF,
                                               bf16* __restrict__ PH,
                                               int KIin, int KIP, int O,
                                               const int* __restrict__ flag) {
  const int idx = blockIdx.x*256 + threadIdx.x;
  if (idx >= ED_*O*KIP) return;
  const int d = idx / (O*KIP), rem = idx - d*O*KIP;
  const int o = rem / KIP, kp = rem - o*KIP;
  int cheb, i; bool valid;
  if (LAYER == 0) {
    cheb = (kp >= 80) ? 1 : 0;
    const int local = kp - cheb*80;
    if (local < 64)       { i = local + 1; valid = true; }
    else if (local == 64) { i = 0;         valid = true; }
    else                  { i = 0;         valid = false; }
  } else {
    cheb = kp >> 7; i = kp & 127; valid = true;
  }
  float v = 0.f;
  if (valid) v = ldin(Wb, (size_t)((d*2 + cheb)*KIin + i)*O + o, flag[0]);
  const int kg = kp >> 2, e = kp & 3;
  const size_t pi = ((size_t)(o*(KIP/4) + kg)*ED_ + d)*4 + e;
  PF[pi] = v;
  PH[pi] = f2b(v);
}

// bias vectors: outv[n][o] = sum_d Ein[n,d]*bb[d][o]
__global__ __launch_bounds__(128) void k_matb(const float* __restrict__ Ein,
                                              const void* __restrict__ bb,
                                              float* __restrict__ outv, int O,
                                              const int* __restrict__ flag) {
  const int n = blockIdx.x, tid = threadIdx.x;
  if (tid >= O) return;
  const int f = flag[0];
  float acc = 0.f;
#pragma unroll
  for (int d = 0; d < ED_; ++d) acc += Ein[n*ED_ + d]*ldin(bb, d*O + tid, f);
  outv[n*O + tid] = acc;
}

// ---------------------------------------------------------------------------
// Small 64-tile fp32 GEMM for Sx0 only (setup; XT form X[c*ldx+m]); cols=192
// ---------------------------------------------------------------------------
__global__ __launch_bounds__(256) void k_gemm64T(const float* __restrict__ S,
                                                 const float* __restrict__ X,
                                                 float* __restrict__ C,
                                                 int ldx, int ldc) {
  const int bm = blockIdx.x * 64;
  const int bc = blockIdx.y * 64;
  __shared__ float St[64][68];
  __shared__ float Xt[64][68];
  const int tid = threadIdx.x;
  const int r0 = (tid >> 4) * 4;
  const int c0 = (tid & 15) * 4;
  float acc[4][4];
#pragma unroll
  for (int i = 0; i < 4; ++i)
#pragma unroll
    for (int j = 0; j < 4; ++j) acc[i][j] = 0.f;
  for (int mk = 0; mk < N_; mk += 64) {
    {
      const int r = tid >> 2, ks = (tid & 3) * 16;
      const float* sp = S + (size_t)(bm + r)*N_ + mk + ks;
#pragma unroll
      for (int u = 0; u < 16; ++u) St[ks + u][r] = sp[u];
      const float* xp = X + (size_t)(bc + r)*ldx + mk + ks;
#pragma unroll
      for (int u = 0; u < 16; ++u) Xt[ks + u][r] = xp[u];
    }
    __syncthreads();
#pragma unroll 4
    for (int kk = 0; kk < 64; ++kk) {
      const float a0 = St[kk][r0], a1 = St[kk][r0+1],
                  a2 = St[kk][r0+2], a3 = St[kk][r0+3];
      const float b0 = Xt[kk][c0], b1 = Xt[kk][c0+1],
                  b2 = Xt[kk][c0+2], b3 = Xt[kk][c0+3];
      acc[0][0] += a0*b0; acc[0][1] += a0*b1; acc[0][2] += a0*b2; acc[0][3] += a0*b3;
      acc[1][0] += a1*b0; acc[1][1] += a1*b1; acc[1][2] += a1*b2; acc[1][3] += a1*b3;
      acc[2][0] += a2*b0; acc[2][1] += a2*b1; acc[2][2] += a2*b2; acc[2][3] += a2*b3;
      acc[3][0] += a3*b0; acc[3][1] += a3*b1; acc[3][2] += a3*b2; acc[3][3] += a3*b3;
    }
    __syncthreads();
  }
#pragma unroll
  for (int i = 0; i < 4; ++i)
#pragma unroll
    for (int j = 0; j < 4; ++j)
      C[(size_t)(bm + r0 + i)*ldc + bc + c0 + j] = acc[i][j];
}

// ---------------------------------------------------------------------------
// Split-bf16 MFMA GEMM (R19): 128x64 tile, BK=64, LDS stride 72 bf16,
// 4 waves each 64x32. Bitwise-identical accumulation order to R14.
// ---------------------------------------------------------------------------
__global__ __launch_bounds__(256) void k_gemmM(const bf16* __restrict__ Sh,
                                               const bf16* __restrict__ Sl,
                                               const bf16* __restrict__ X1h,
                                               const bf16* __restrict__ X1l,
                                               float* __restrict__ C1, int ldc1,
                                               const bf16* __restrict__ X2h,
                                               const bf16* __restrict__ X2l,
                                               float* __restrict__ C2, int ldc2,
                                               int split) {
  const int bm = blockIdx.x * 128;
  int bc = blockIdx.y * 64;
  const bf16* Xh = X1h; const bf16* Xl = X1l; float* C = C1; int ldc = ldc1;
  if (bc >= split) { Xh = X2h; Xl = X2l; C = C2; ldc = ldc2; bc -= split; }

  __shared__ __align__(16) bf16 Ah[128][72];
  __shared__ __align__(16) bf16 Al[128][72];
  __shared__ __align__(16) bf16 Bh[64][72];
  __shared__ __align__(16) bf16 Bl[64][72];
  const int tid = threadIdx.x;
  const int wave = tid >> 6, lane = tid & 63, q = lane >> 4, ln = lane & 15;
  const int wm = wave >> 1, wn = wave & 1;            // wave quadrant 2x2
  const int srow = tid >> 3, scol = (tid & 7) * 8;    // staging: 32 rows/pass

  floatx4 acc[4][2];
#pragma unroll
  for (int mt = 0; mt < 4; ++mt)
#pragma unroll
    for (int nt = 0; nt < 2; ++nt) acc[mt][nt] = (floatx4){0.f,0.f,0.f,0.f};

  for (int mk = 0; mk < N_; mk += 64) {
#pragma unroll
    for (int i = 0; i < 4; ++i) {
      const int r = i*32 + srow;
      *(uint4*)&Ah[r][scol] = *(const uint4*)(Sh + (size_t)(bm + r)*N_ + mk + scol);
      *(uint4*)&Al[r][scol] = *(const uint4*)(Sl + (size_t)(bm + r)*N_ + mk + scol);
    }
#pragma unroll
    for (int i = 0; i < 2; ++i) {
      const int r = i*32 + srow;
      *(uint4*)&Bh[r][scol] = *(const uint4*)(Xh + (size_t)(bc + r)*N_ + mk + scol);
      *(uint4*)&Bl[r][scol] = *(const uint4*)(Xl + (size_t)(bc + r)*N_ + mk + scol);
    }
    __syncthreads();
#pragma unroll
    for (int ks = 0; ks < 64; ks += 32) {
      short8 ah[4], al[4], bh[2], bl[2];
#pragma unroll
      for (int mt = 0; mt < 4; ++mt) {
        ah[mt] = *(const short8*)&Ah[wm*64 + mt*16 + ln][ks + q*8];
        al[mt] = *(const short8*)&Al[wm*64 + mt*16 + ln][ks + q*8];
      }
#pragma unroll
      for (int nt = 0; nt < 2; ++nt) {
        bh[nt] = *(const short8*)&Bh[wn*32 + nt*16 + ln][ks + q*8];
        bl[nt] = *(const short8*)&Bl[wn*32 + nt*16 + ln][ks + q*8];
      }
#pragma unroll
      for (int mt = 0; mt < 4; ++mt)
#pragma unroll
        for (int nt = 0; nt < 2; ++nt) {
          acc[mt][nt] = __builtin_amdgcn_mfma_f32_16x16x32_bf16(ah[mt], bh[nt], acc[mt][nt], 0, 0, 0);
          acc[mt][nt] = __builtin_amdgcn_mfma_f32_16x16x32_bf16(al[mt], bh[nt], acc[mt][nt], 0, 0, 0);
          acc[mt][nt] = __builtin_amdgcn_mfma_f32_16x16x32_bf16(ah[mt], bl[nt], acc[mt][nt], 0, 0, 0);
        }
    }
    __syncthreads();
  }
#pragma unroll
  for (int mt = 0; mt < 4; ++mt)
#pragma unroll
    for (int nt = 0; nt < 2; ++nt)
#pragma unroll
      for (int r = 0; r < 4; ++r)
        C[(size_t)(bm + wm*64 + mt*16 + q*4 + r)*ldc + bc + wn*32 + nt*16 + ln] =
            acc[mt][nt][r];
}

// ---------------------------------------------------------------------------
// xg builder (float4): xg[b][k], padded row stride KIPP (R13 verbatim).
// ---------------------------------------------------------------------------
template<int LAYER, int KIP, int KIPP>
__device__ __forceinline__ void build4(float (*xg)[KIPP],
                                       const float* p0, const float* p1,
                                       const float* p2, const float* p3,
                                       int n, int t, int tid) {
  constexpr int NQ = KIP/4;
  for (int idx = tid; idx < B_*NQ; idx += 256) {
    const int b = idx / NQ, k = (idx - b*NQ) * 4;
    float4 v = make_float4(0.f, 0.f, 0.f, 0.f);
    if (LAYER == 1) {
      const float* rg = (k < 64) ? p0 : (k < 128) ? p1 : (k < 192) ? p2 : p3;
      v = *(const float4*)(rg + (size_t)n*BH + b*64 + (k & 63));
    } else {
      if (k < 64)        v = *(const float4*)(p0 + (size_t)n*BH + b*64 + k);
      else if (k == 64)  v.x = p1[(size_t)(b*T_ + t)*N_ + n];
      else if (k >= 80 && k < 144)
                         v = *(const float4*)(p2 + (size_t)n*BH + b*64 + (k - 80));
      else if (k == 144) v.x = p3[(size_t)n*BT + b*T_ + t];
    }
    *(float4*)&xg[b][k] = v;
  }
}

// Packed merge (R13 verbatim)
template<int KIP>
__device__ __forceinline__ float4 merge_p(const float* __restrict__ PF,
                                          const bf16* __restrict__ PH,
                                          const float* el, int o, int kg,
                                          int isbf) {
  float4 a4 = make_float4(0.f, 0.f, 0.f, 0.f);
  const size_t gbase = (size_t)(o*(KIP/4) + kg)*(ED_*4);
  if (isbf) {
    const uint4* g = (const uint4*)(PH + gbase);
#pragma unroll
    for (int i = 0; i < 5; ++i) {
      const uint4 w = g[i];
      const float e0 = el[2*i], e1 = el[2*i + 1];
      a4.x += e0*bits2f(w.x & 0xFFFFu); a4.y += e0*bits2f(w.x >> 16);
      a4.z += e0*bits2f(w.y & 0xFFFFu); a4.w += e0*bits2f(w.y >> 16);
      a4.x += e1*bits2f(w.z & 0xFFFFu); a4.y += e1*bits2f(w.z >> 16);
      a4.z += e1*bits2f(w.w & 0xFFFFu); a4.w += e1*bits2f(w.w >> 16);
    }
  } else {
    const float4* g = (const float4*)(PF + gbase);
#pragma unroll
    for (int d = 0; d < ED_; ++d)
      fma4(a4, el[d], g[d]);
  }
  return a4;
}

// R18: dual-n merge — one basis load feeds both n's accumulators. Per-n
// accumulation order identical to merge_p (bitwise-identical results).
template<int KIP>
__device__ __forceinline__ void merge_p2(const float* __restrict__ PF,
                                         const bf16* __restrict__ PH,
                                         const float* el0, const float* el1,
                                         int o, int kg, int isbf,
                                         float4& a0, float4& a1) {
  const size_t gbase = (size_t)(o*(KIP/4) + kg)*(ED_*4);
  if (isbf) {
    const uint4* g = (const uint4*)(PH + gbase);
#pragma unroll
    for (int i = 0; i < 5; ++i) {
      const uint4 w = g[i];
      const float f0 = bits2f(w.x & 0xFFFFu), f1 = bits2f(w.x >> 16);
      const float f2 = bits2f(w.y & 0xFFFFu), f3 = bits2f(w.y >> 16);
      const float f4 = bits2f(w.z & 0xFFFFu), f5 = bits2f(w.z >> 16);
      const float f6 = bits2f(w.w & 0xFFFFu), f7 = bits2f(w.w >> 16);
      const float e00 = el0[2*i], e01 = el0[2*i + 1];
      const float e10 = el1[2*i], e11 = el1[2*i + 1];
      a0.x += e00*f0; a0.y += e00*f1; a0.z += e00*f2; a0.w += e00*f3;
      a0.x += e01*f4; a0.y += e01*f5; a0.z += e01*f6; a0.w += e01*f7;
      a1.x += e10*f0; a1.y += e10*f1; a1.z += e10*f2; a1.w += e10*f3;
      a1.x += e11*f4; a1.y += e11*f5; a1.z += e11*f6; a1.w += e11*f7;
    }
  } else {
    const float4* g = (const float4*)(PF + gbase);
#pragma unroll
    for (int d = 0; d < ED_; ++d) {
      const float4 w = g[d];
      fma4(a0, el0[d], w);
      fma4(a1, el1[d], w);
    }
  }
}

// ---------------------------------------------------------------------------
// R15: one-time merged-weight build. WM[n][o][k] (k contiguous), fp32.
// ---------------------------------------------------------------------------
template<int KIP>
__global__ __launch_bounds__(256) void k_merge(const float* __restrict__ PF,
                                               const bf16* __restrict__ PH,
                                               const float* __restrict__ Ein,
                                               float* __restrict__ WM, int O,
                                               const int* __restrict__ flag) {
  const int n = blockIdx.x;
  const int idx = blockIdx.y*256 + threadIdx.x;
  __shared__ float es[ED_];
  if (threadIdx.x < ED_) es[threadIdx.x] = Ein[n*ED_ + threadIdx.x];
  __syncthreads();
  if (idx >= O*(KIP/4)) return;
  const int o = idx / (KIP/4), kg = idx - o*(KIP/4);
  float el[ED_];
#pragma unroll
  for (int d = 0; d < ED_; ++d) el[d] = es[d];
  const float4 a4 = merge_p<KIP>(PF, PH, el, o, kg, flag[0]);
  *(float4*)&WM[((size_t)n*O + o)*KIP + kg*4] = a4;
}

// ---------------------------------------------------------------------------
// Gate (premerged, R16): simple stage->barrier->compute->barrier stream.
// ---------------------------------------------------------------------------
template<int LAYER, int KIP>
__global__ __launch_bounds__(256, 2) void k_gateWpm(const float* __restrict__ WM,
                                                    const float* __restrict__ bgv,
                                                    const float* __restrict__ p0,
                                                    const float* __restrict__ p1,
                                                    const float* __restrict__ p2,
                                                    const float* __restrict__ p3,
                                                    const float* __restrict__ hstate,
                                                    float* __restrict__ zh,
                                                    bf16* __restrict__ zhTh,
                                                    bf16* __restrict__ zhTl,
                                                    float* __restrict__ r_buf,
                                                    int t) {
  constexpr int KIPP = KIP + 4;
  constexpr int O = 128;
  const int n = blockIdx.x, tid = threadIdx.x;
  __shared__ float xg[B_][KIPP];
  __shared__ float wm[O][36];
  build4<LAYER, KIP, KIPP>(xg, p0, p1, p2, p3, n, t, tid);

  const float* WMn = WM + (size_t)n*O*KIP;
  const int b = tid >> 4, q = tid & 15;
  float acc[8];
#pragma unroll
  for (int j = 0; j < 8; ++j) acc[j] = 0.f;

  for (int k0 = 0; k0 < KIP; k0 += 32) {
#pragma unroll
    for (int i = 0; i < O*8/256; ++i) {
      const int idx = tid + i*256;
      const int o = idx >> 3, kq = idx & 7;
      *(float4*)&wm[o][kq*4] =
          *(const float4*)(WMn + (size_t)o*KIP + k0 + kq*4);
    }
    __syncthreads();   // wm ready (and xg on first iter)
#pragma unroll
    for (int kq = 0; kq < 8; ++kq) {
      const float4 xv = *(const float4*)&xg[b][k0 + kq*4];
#pragma unroll
      for (int j = 0; j < 8; ++j) {
        const float4 wv = *(const float4*)&wm[q + 16*j][kq*4];
        acc[j] += xv.x*wv.x + xv.y*wv.y + xv.z*wv.z + xv.w*wv.w;
      }
    }
    __syncthreads();
  }
#pragma unroll
  for (int j = 0; j < 8; ++j) {
    const int o = q + 16*j;
    float s = acc[j] + bgv[n*128 + o];
    s = 1.f/(1.f + __expf(-s));
    if (o < HID_) {
      const float zv = s*hstate[(size_t)n*BH + b*64 + o];
      zh[(size_t)n*BH + b*64 + o] = zv;
      const bf16 h = f2b(zv);
      zhTh[(size_t)(b*64 + o)*N_ + n] = h;
      zhTl[(size_t)(b*64 + o)*N_ + n] = f2b(zv - b2f(h));
    } else {
      r_buf[(size_t)n*BH + b*64 + (o - HID_)] = s;
    }
  }
}

// ---------------------------------------------------------------------------
// Candidate (premerged, R16): same simple stream structure.
// ---------------------------------------------------------------------------
template<int LAYER, int KIP>
__global__ __launch_bounds__(256, 2) void k_candWpm(const float* __restrict__ WM,
                                                    const float* __restrict__ buv,
                                                    const float* __restrict__ p0,
                                                    const float* __restrict__ p1,
                                                    const float* __restrict__ p2,
                                                    const float* __restrict__ p3,
                                                    const float* __restrict__ r_buf,
                                                    float* __restrict__ hstate,
                                                    bf16* __restrict__ hTh,
                                                    bf16* __restrict__ hTl,
                                                    int t) {
  constexpr int KIPP = KIP + 4;
  constexpr int O = 64;
  const int n = blockIdx.x, tid = threadIdx.x;
  __shared__ float xg[B_][KIPP];
  __shared__ float wm[O][36];
  build4<LAYER, KIP, KIPP>(xg, p0, p1, p2, p3, n, t, tid);

  const float* WMn = WM + (size_t)n*O*KIP;
  const int b = tid >> 4, q = tid & 15;
  float acc[4];
#pragma unroll
  for (int j = 0; j < 4; ++j) acc[j] = 0.f;

  for (int k0 = 0; k0 < KIP; k0 += 32) {
#pragma unroll
    for (int i = 0; i < O*8/256; ++i) {
      const int idx = tid + i*256;
      const int o = idx >> 3, kq = idx & 7;
      *(float4*)&wm[o][kq*4] =
          *(const float4*)(WMn + (size_t)o*KIP + k0 + kq*4);
    }
    __syncthreads();
#pragma unroll
    for (int kq = 0; kq < 8; ++kq) {
      const float4 xv = *(const float4*)&xg[b][k0 + kq*4];
#pragma unroll
      for (int j = 0; j < 4; ++j) {
        const float4 wv = *(const float4*)&wm[q + 16*j][kq*4];
        acc[j] += xv.x*wv.x + xv.y*wv.y + xv.z*wv.z + xv.w*wv.w;
      }
    }
    __syncthreads();
  }
#pragma unroll
  for (int j = 0; j < 4; ++j) {
    const int o = q + 16*j;
    const float hc = tanhf(acc[j] + buv[n*64 + o]);
    const float rr = r_buf[(size_t)n*BH + b*64 + o];
    const float hold = hstate[(size_t)n*BH + b*64 + o];
    const float hn = rr*hold + (1.f - rr)*hc;
    hstate[(size_t)n*BH + b*64 + o] = hn;
    const bf16 h = f2b(hn);
    hTh[(size_t)(b*64 + o)*N_ + n] = h;
    hTl[(size_t)(b*64 + o)*N_ + n] = f2b(hn - b2f(h));
  }
}

// ---------------------------------------------------------------------------
// R23: Gate fallback, TWO n per block, FULL upfront xg, O-SPLIT wm staging:
// per k-chunk {merge o in [0,64) -> sync -> dot j=0..3 -> sync ->
// merge o in [64,128) -> sync -> dot j=4..7 -> sync}. Same gathers, same
// per-acc[j] k-order -> bitwise-same. LDS 70->52KB (KIP=256) / 58->39KB.
// ---------------------------------------------------------------------------
template<int LAYER, int KIP>
__global__ __launch_bounds__(256, 3) void k_gateW2(const float* __restrict__ PF,
                                                   const bf16* __restrict__ PH,
                                                   const float* __restrict__ bgv,
                                                   const float* __restrict__ p0,
                                                   const float* __restrict__ p1,
                                                   const float* __restrict__ p2,
                                                   const float* __restrict__ p3,
                                                   const float* __restrict__ Ein,
                                                   const float* __restrict__ hstate,
                                                   float* __restrict__ zh,
                                                   bf16* __restrict__ zhTh,
                                                   bf16* __restrict__ zhTl,
                                                   float* __restrict__ r_buf,
                                                   const int* __restrict__ flag,
                                                   int t) {
  constexpr int KIPP = KIP + 4;
  const int n0 = blockIdx.x, n1 = blockIdx.x + N_/2, tid = threadIdx.x;
  __shared__ float xg[2][B_][KIPP];
  __shared__ float wm[2][64][36];         // o-half at a time
  __shared__ float es[2][ED_];
  if (tid < ED_) es[0][tid] = Ein[n0*ED_ + tid];
  if (tid >= 32 && tid < 32 + ED_) es[1][tid - 32] = Ein[n1*ED_ + (tid - 32)];
  build4<LAYER, KIP, KIPP>(xg[0], p0, p1, p2, p3, n0, t, tid);
  build4<LAYER, KIP, KIPP>(xg[1], p0, p1, p2, p3, n1, t, tid);
  __syncthreads();
  const int isbf = flag[0];
  float el0[ED_], el1[ED_];
#pragma unroll
  for (int d = 0; d < ED_; ++d) { el0[d] = es[0][d]; el1[d] = es[1][d]; }

  const int b = tid >> 4, q = tid & 15;
  float ac0[8], ac1[8];
#pragma unroll
  for (int j = 0; j < 8; ++j) { ac0[j] = 0.f; ac1[j] = 0.f; }

  for (int k0 = 0; k0 < KIP; k0 += 32) {
#pragma unroll
    for (int half = 0; half < 2; ++half) {
      // merge this o-half (64 o x 8 kq = 512 slots, 2 per thread)
#pragma unroll
      for (int i = 0; i < 2; ++i) {
        const int idx = tid + i*256;
        const int os = idx >> 3, kq = idx & 7;
        float4 a0 = make_float4(0.f, 0.f, 0.f, 0.f);
        float4 a1 = make_float4(0.f, 0.f, 0.f, 0.f);
        merge_p2<KIP>(PF, PH, el0, el1, half*64 + os, (k0 >> 2) + kq, isbf,
                      a0, a1);
        *(float4*)&wm[0][os][kq*4] = a0;
        *(float4*)&wm[1][os][kq*4] = a1;
      }
      __syncthreads();
#pragma unroll
      for (int kq = 0; kq < 8; ++kq) {
        const float4 xv0 = *(const float4*)&xg[0][b][k0 + kq*4];
        const float4 xv1 = *(const float4*)&xg[1][b][k0 + kq*4];
#pragma unroll
        for (int jj = 0; jj < 4; ++jj) {
          const int j = half*4 + jj;
          const float4 w0 = *(const float4*)&wm[0][q + 16*jj][kq*4];
          const float4 w1 = *(const float4*)&wm[1][q + 16*jj][kq*4];
          ac0[j] += xv0.x*w0.x + xv0.y*w0.y + xv0.z*w0.z + xv0.w*w0.w;
          ac1[j] += xv1.x*w1.x + xv1.y*w1.y + xv1.z*w1.z + xv1.w*w1.w;
        }
      }
      __syncthreads();
    }
  }
#pragma unroll
  for (int j = 0; j < 8; ++j) {
    const int o = (j & 1)*0 + ((j < 4) ? (q + 16*j) : (q + 16*j));
    (void)o;
  }
#pragma unroll
  for (int j = 0; j < 8; ++j) {
    const int o = q + 16*j;
    {
      float s = ac0[j] + bgv[n0*128 + o];
      s = 1.f/(1.f + __expf(-s));
      if (o < HID_) {
        const float zv = s*hstate[(size_t)n0*BH + b*64 + o];
        zh[(size_t)n0*BH + b*64 + o] = zv;
        const bf16 h = f2b(zv);
        zhTh[(size_t)(b*64 + o)*N_ + n0] = h;
        zhTl[(size_t)(b*64 + o)*N_ + n0] = f2b(zv - b2f(h));
      } else {
        r_buf[(size_t)n0*BH + b*64 + (o - HID_)] = s;
      }
    }
    {
      float s = ac1[j] + bgv[n1*128 + o];
      s = 1.f/(1.f + __expf(-s));
      if (o < HID_) {
        const float zv = s*hstate[(size_t)n1*BH + b*64 + o];
        zh[(size_t)n1*BH + b*64 + o] = zv;
        const bf16 h = f2b(zv);
        zhTh[(size_t)(b*64 + o)*N_ + n1] = h;
        zhTl[(size_t)(b*64 + o)*N_ + n1] = f2b(zv - b2f(h));
      } else {
        r_buf[(size_t)n1*BH + b*64 + (o - HID_)] = s;
      }
    }
  }
}

// ---------------------------------------------------------------------------
// R23: Candidate fallback, TWO n per block, FULL upfront xg, O-SPLIT wm:
// per k-chunk {merge o in [0,32) -> sync -> dot j=0..1 -> sync ->
// merge o in [32,64) -> sync -> dot j=2..3 -> sync}. Bitwise-same.
// ---------------------------------------------------------------------------
template<int LAYER, int KIP>
__global__ __launch_bounds__(256, 3) void k_candW2f(const float* __restrict__ PF,
                                                    const bf16* __restrict__ PH,
                                                    const float* __restrict__ buv,
                                                    const float* __restrict__ p0,
                                                    const float* __restrict__ p1,
                                                    const float* __restrict__ p2,
                                                    const float* __restrict__ p3,
                                                    const float* __restrict__ Ein,
                                                    const float* __restrict__ r_buf,
                                                    float* __restrict__ hstate,
                                                    bf16* __restrict__ hTh,
                                                    bf16* __restrict__ hTl,
                                                    const int* __restrict__ flag,
                                                    int t) {
  constexpr int KIPP = KIP + 4;
  const int n0 = blockIdx.x, n1 = blockIdx.x + N_/2, tid = threadIdx.x;
  __shared__ float xg[2][B_][KIPP];
  __shared__ float wm[2][32][36];         // o-half at a time
  __shared__ float es[2][ED_];
  if (tid < ED_) es[0][tid] = Ein[n0*ED_ + tid];
  if (tid >= 32 && tid < 32 + ED_) es[1][tid - 32] = Ein[n1*ED_ + (tid - 32)];
  build4<LAYER, KIP, KIPP>(xg[0], p0, p1, p2, p3, n0, t, tid);
  build4<LAYER, KIP, KIPP>(xg[1], p0, p1, p2, p3, n1, t, tid);
  __syncthreads();
  const int isbf = flag[0];
  float el0[ED_], el1[ED_];
#pragma unroll
  for (int d = 0; d < ED_; ++d) { el0[d] = es[0][d]; el1[d] = es[1][d]; }

  const int b = tid >> 4, q = tid & 15;
  float ac0[4], ac1[4];
#pragma unroll
  for (int j = 0; j < 4; ++j) { ac0[j] = 0.f; ac1[j] = 0.f; }

  for (int k0 = 0; k0 < KIP; k0 += 32) {
#pragma unroll
    for (int half = 0; half < 2; ++half) {
      // merge this o-half (32 o x 8 kq = 256 slots, 1 per thread)
      {
        const int os = tid >> 3, kq = tid & 7;
        float4 a0 = make_float4(0.f, 0.f, 0.f, 0.f);
        float4 a1 = make_float4(0.f, 0.f, 0.f, 0.f);
        merge_p2<KIP>(PF, PH, el0, el1, half*32 + os, (k0 >> 2) + kq, isbf,
                      a0, a1);
        *(float4*)&wm[0][os][kq*4] = a0;
        *(float4*)&wm[1][os][kq*4] = a1;
      }
      __syncthreads();
#pragma unroll
      for (int kq = 0; kq < 8; ++kq) {
        const float4 xv0 = *(const float4*)&xg[0][b][k0 + kq*4];
        const float4 xv1 = *(const float4*)&xg[1][b][k0 + kq*4];
#pragma unroll
        for (int jj = 0; jj < 2; ++jj) {
          const int j = half*2 + jj;
          const float4 w0 = *(const float4*)&wm[0][q + 16*jj][kq*4];
          const float4 w1 = *(const float4*)&wm[1][q + 16*jj][kq*4];
          ac0[j] += xv0.x*w0.x + xv0.y*w0.y + xv0.z*w0.z + xv0.w*w0.w;
          ac1[j] += xv1.x*w1.x + xv1.y*w1.y + xv1.z*w1.z + xv1.w*w1.w;
        }
      }
      __syncthreads();
    }
  }
#pragma unroll
  for (int j = 0; j < 4; ++j) {
    const int o = q + 16*j;
    {
      const float hc = tanhf(ac0[j] + buv[n0*64 + o]);
      const float rr = r_buf[(size_t)n0*BH + b*64 + o];
      const float hold = hstate[(size_t)n0*BH + b*64 + o];
      const float hn = rr*hold + (1.f - rr)*hc;
      hstate[(size_t)n0*BH + b*64 + o] = hn;
      const bf16 h = f2b(hn);
      hTh[(size_t)(b*64 + o)*N_ + n0] = h;
      hTl[(size_t)(b*64 + o)*N_ + n0] = f2b(hn - b2f(h));
    }
    {
      const float hc = tanhf(ac1[j] + buv[n1*64 + o]);
      const float rr = r_buf[(size_t)n1*BH + b*64 + o];
      const float hold = hstate[(size_t)n1*BH + b*64 + o];
      const float hn = rr*hold + (1.f - rr)*hc;
      hstate[(size_t)n1*BH + b*64 + o] = hn;
      const bf16 h = f2b(hn);
      hTh[(size_t)(b*64 + o)*N_ + n1] = h;
      hTl[(size_t)(b*64 + o)*N_ + n1] = f2b(hn - b2f(h));
    }
  }
}

__global__ void k_zero_f(float* __restrict__ p, int n) {
  const int i = blockIdx.x*256 + threadIdx.x;
  if (i < n) p[i] = 0.f;
}
__global__ void k_zero_out(void* __restrict__ out, int nelem,
                           const int* __restrict__ flag) {
  const int i = blockIdx.x*256 + threadIdx.x;
  if (i < nelem) {
    if (flag[0]) ((unsigned short*)out)[i] = 0;
    else         ((float*)out)[i] = 0.f;
  }
}

// out[b][hor][n] = sum_c h2[n][b*64+c]*cwf[hor][c] + cbf[hor]
__global__ __launch_bounds__(256) void k_conv(const float* __restrict__ h2,
                                              const float* __restrict__ cwf,
                                              const float* __restrict__ cbf,
                                              void* __restrict__ out,
                                              const int* __restrict__ flag) {
  const int n = blockIdx.x, tid = threadIdx.x;
  __shared__ float hs[BH];
  for (int i = tid; i < BH; i += 256) hs[i] = h2[(size_t)n*BH + i];
  __syncthreads();
  const int isbf = flag[0];
  for (int i = tid; i < B_*HOR_; i += 256) {
    const int b = i / HOR_, hor = i - b*HOR_;
    float acc = cbf[hor];
#pragma unroll
    for (int c = 0; c < HID_; ++c) acc += hs[b*HID_ + c]*cwf[hor*HID_ + c];
    const size_t oi = (size_t)(b*HOR_ + hor)*N_ + n;
    if (isbf) ((bf16*)out)[oi] = f2b(acc);
    else      ((float*)out)[oi] = acc;
  }
}

// ---------------------------------------------------------------------------
extern "C" void kernel_launch(void* const* d_in, const int* in_sizes, int n_in,
                              void* d_out, int out_size, void* d_ws, size_t ws_size,
                              hipStream_t stream) {
  const void* src = d_in[0];
  const void* E   = d_in[1];
  const void* Wg0 = d_in[2];
  const void* bg0 = d_in[3];
  const void* Wu0 = d_in[4];
  const void* bu0 = d_in[5];
  const void* Wg1 = d_in[6];
  const void* bg1 = d_in[7];
  const void* Wu1 = d_in[8];
  const void* bu1 = d_in[9];
  const void* cw  = d_in[10];
  const void* cb  = d_in[11];
  (void)in_sizes; (void)n_in;

  char* p = (char*)d_ws;
  char* ws_end = (char*)d_ws + ws_size;
  auto alloc = [&](size_t bytes) -> char* {
    char* r = p; p += (bytes + 255) & ~(size_t)255; return r;
  };
  const size_t SL = (size_t)N_*BH;
  int*   flag  = (int*)  alloc(256);
  float* Ein   = (float*)alloc((size_t)N_*ED_*4);
  float* cwf   = (float*)alloc((size_t)HOR_*HID_*4);
  float* cbf   = (float*)alloc((size_t)HOR_*4);
  float* S_f   = (float*)alloc((size_t)N_*N_*4);
  bf16*  S_hi  = (bf16*) alloc((size_t)N_*N_*2);
  bf16*  S_lo  = (bf16*) alloc((size_t)N_*N_*2);
  float* Wg0F  = (float*)alloc((size_t)ED_*128*160*4);
  float* Wu0F  = (float*)alloc((size_t)ED_*64*160*4);
  float* Wg1F  = (float*)alloc((size_t)ED_*128*256*4);
  float* Wu1F  = (float*)alloc((size_t)ED_*64*256*4);
  bf16*  Wg0H  = (bf16*) alloc((size_t)ED_*128*160*2);
  bf16*  Wu0H  = (bf16*) alloc((size_t)ED_*64*160*2);
  bf16*  Wg1H  = (bf16*) alloc((size_t)ED_*128*256*2);
  bf16*  Wu1H  = (bf16*) alloc((size_t)ED_*64*256*2);
  float* bgv0  = (float*)alloc((size_t)N_*128*4);
  float* buv0  = (float*)alloc((size_t)N_*64*4);
  float* bgv1  = (float*)alloc((size_t)N_*128*4);
  float* buv1  = (float*)alloc((size_t)N_*64*4);
  float* srcf  = (float*)alloc((size_t)BT*N_*4);
  float* Sx0   = (float*)alloc((size_t)N_*BT*4);
  float* h0    = (float*)alloc(SL*4);              // h0,h2 adjacent (one zero)
  float* h2    = (float*)alloc(SL*4);
  float* Sh_a  = (float*)alloc(SL*4);              // Sh_a,Sh_b adjacent
  float* Sh_b  = (float*)alloc(SL*4);
  float* zh    = (float*)alloc(SL*4);
  float* r_buf = (float*)alloc(SL*4);
  bf16*  zhTh  = (bf16*) alloc(SL*2);
  bf16*  zhTl  = (bf16*) alloc(SL*2);
  bf16*  h0Th  = (bf16*) alloc(SL*2);
  bf16*  h0Tl  = (bf16*) alloc(SL*2);
  bf16*  h2Th  = (bf16*) alloc(SL*2);
  bf16*  h2Tl  = (bf16*) alloc(SL*2);

  const size_t required_base = (size_t)(p - (char*)d_ws);

  // --- premerged weight tiers (optional; per-buffer fallback) ---
  float* Wu0M = (float*)alloc((size_t)N_*64*160*4);   bool pmWu0 = (p <= ws_end);
  float* Wu1M = (float*)alloc((size_t)N_*64*256*4);   bool pmWu1 = (p <= ws_end);
  float* Wg0M = (float*)alloc((size_t)N_*128*160*4);  bool pmWg0 = (p <= ws_end);
  float* Wg1M = (float*)alloc((size_t)N_*128*256*4);  bool pmWg1 = (p <= ws_end);

  auto cdiv = [](int a, int b) { return (a + b - 1) / b; };

  k_detect<<<dim3(1), 256, 0, stream>>>(E, flag);

  if (required_base > ws_size) {
    k_zero_out<<<dim3(cdiv(out_size, 256)), 256, 0, stream>>>(d_out, out_size, flag);
    return;
  }

  // --- casts + setup ---
  k_castE  <<<dim3(cdiv(N_*ED_, 256)), 256, 0, stream>>>(E, Ein, flag);
  k_castsrc<<<dim3(cdiv(BT*N_, 256)),  256, 0, stream>>>(src, srcf, flag);
  k_castc  <<<dim3(cdiv(HOR_*HID_, 256)), 256, 0, stream>>>(cw, cb, cwf, cbf, flag);
  k_prepP<0><<<dim3(cdiv(ED_*128*160, 256)), 256, 0, stream>>>(Wg0, Wg0F, Wg0H, 65, 160, 128, flag);
  k_prepP<0><<<dim3(cdiv(ED_*64*160,  256)), 256, 0, stream>>>(Wu0, Wu0F, Wu0H, 65, 160, 64, flag);
  k_prepP<1><<<dim3(cdiv(ED_*128*256, 256)), 256, 0, stream>>>(Wg1, Wg1F, Wg1H, 128, 256, 128, flag);
  k_prepP<1><<<dim3(cdiv(ED_*64*256,  256)), 256, 0, stream>>>(Wu1, Wu1F, Wu1H, 128, 256, 64, flag);
  k_matb<<<dim3(N_), 128, 0, stream>>>(Ein, bg0, bgv0, 128, flag);
  k_matb<<<dim3(N_), 128, 0, stream>>>(Ein, bu0, buv0, 64,  flag);
  k_matb<<<dim3(N_), 128, 0, stream>>>(Ein, bg1, bgv1, 128, flag);
  k_matb<<<dim3(N_), 128, 0, stream>>>(Ein, bu1, buv1, 64,  flag);
  k_softmax_S<<<dim3(N_), 256, 0, stream>>>(Ein, S_f);
  k_splitS<<<dim3(cdiv(N_*N_, 256)), 256, 0, stream>>>(S_f, S_hi, S_lo, N_*N_);

  // --- one-time merged weights (R15) ---
  if (pmWu0) k_merge<160><<<dim3(N_, 10), 256, 0, stream>>>(Wu0F, Wu0H, Ein, Wu0M, 64,  flag);
  if (pmWu1) k_merge<256><<<dim3(N_, 16), 256, 0, stream>>>(Wu1F, Wu1H, Ein, Wu1M, 64,  flag);
  if (pmWg0) k_merge<160><<<dim3(N_, 20), 256, 0, stream>>>(Wg0F, Wg0H, Ein, Wg0M, 128, flag);
  if (pmWg1) k_merge<256><<<dim3(N_, 32), 256, 0, stream>>>(Wg1F, Wg1H, Ein, Wg1M, 128, flag);

  // Sx0[n, bt] = sum_m S[n,m]*srcf[bt*N + m]  (setup, fp32 kernel)
  k_gemm64T<<<dim3(N_/64, BT/64), 256, 0, stream>>>(S_f, srcf, Sx0, N_, BT);

  // zero recurrent states + Sh_a/Sh_b (adjacent pairs; t=0 reads them)
  k_zero_f<<<dim3((int)((2*SL + 255)/256)), 256, 0, stream>>>(h0, (int)(2*SL));
  k_zero_f<<<dim3((int)((2*SL + 255)/256)), 256, 0, stream>>>(Sh_a, (int)(2*SL));

  // --- per-role launchers (premerged if the buffer fit, else per-t merge) ---
  auto run_gate0 = [&](int t) {
    if (pmWg0)
      k_gateWpm<0,160><<<dim3(N_), 256, 0, stream>>>(Wg0M, bgv0, h0, srcf, Sh_a, Sx0,
                                                     h0, zh, zhTh, zhTl, r_buf, t);
    else
      k_gateW2<0,160><<<dim3(N_/2), 256, 0, stream>>>(Wg0F, Wg0H, bgv0, h0, srcf, Sh_a, Sx0,
                                                      Ein, h0, zh, zhTh, zhTl, r_buf, flag, t);
  };
  auto run_cand0 = [&](int t) {
    if (pmWu0)
      k_candWpm<0,160><<<dim3(N_), 256, 0, stream>>>(Wu0M, buv0, zh, srcf, Sh_b, Sx0,
                                                     r_buf, h0, h0Th, h0Tl, t);
    else
      k_candW2f<0,160><<<dim3(N_/2), 256, 0, stream>>>(Wu0F, Wu0H, buv0, zh, srcf, Sh_b, Sx0,
                                                       Ein, r_buf, h0, h0Th, h0Tl, flag, t);
  };
  auto run_gate1 = [&](int t) {
    if (pmWg1)
      k_gateWpm<1,256><<<dim3(N_), 256, 0, stream>>>(Wg1M, bgv1, h0, h2, Sh_a, Sh_b,
                                                     h2, zh, zhTh, zhTl, r_buf, t);
    else
      k_gateW2<1,256><<<dim3(N_/2), 256, 0, stream>>>(Wg1F, Wg1H, bgv1, h0, h2, Sh_a, Sh_b,
                                                      Ein, h2, zh, zhTh, zhTl, r_buf, flag, t);
  };
  auto run_cand1 = [&](int t) {
    if (pmWu1)
      k_candWpm<1,256><<<dim3(N_), 256, 0, stream>>>(Wu1M, buv1, h0, zh, Sh_a, Sh_b,
                                                     r_buf, h2, h2Th, h2Tl, t);
    else
      k_candW2f<1,256><<<dim3(N_/2), 256, 0, stream>>>(Wu1F, Wu1H, buv1, h0, zh, Sh_a, Sh_b,
                                                       Ein, r_buf, h2, h2Th, h2Tl, flag, t);
  };

  // --- t = 0 (states zero: all Sh terms vanish except S@h1[0]) ---
  run_gate0(0);
  run_cand0(0);
  // Sh_a = S@h1[0]
  k_gemmM<<<dim3(N_/128, BH/64), 256, 0, stream>>>(S_hi, S_lo, h0Th, h0Tl, Sh_a, BH,
                                                   h0Th, h0Tl, Sh_a, BH, 1 << 30);
  run_gate1(0);
  run_cand1(0);

  // --- t >= 1: Sh_a from previous step's dual GEMM serves L0's S@h ---
  for (int t = 1; t < T_; ++t) {
    run_gate0(t);
    // Szh0 -> Sh_b
    k_gemmM<<<dim3(N_/128, BH/64), 256, 0, stream>>>(S_hi, S_lo, zhTh, zhTl, Sh_b, BH,
                                                     zhTh, zhTl, Sh_b, BH, 1 << 30);
    run_cand0(t);
    // h0 now holds h1[:, t]; dual: Sh_a = S@h1t, Sh_b = S@h2
    k_gemmM<<<dim3(N_/128, 2*BH/64), 256, 0, stream>>>(S_hi, S_lo, h0Th, h0Tl, Sh_a, BH,
                                                       h2Th, h2Tl, Sh_b, BH, BH);
    run_gate1(t);
    // Szh1 -> Sh_b
    k_gemmM<<<dim3(N_/128, BH/64), 256, 0, stream>>>(S_hi, S_lo, zhTh, zhTl, Sh_b, BH,
                                                     zhTh, zhTl, Sh_b, BH, 1 << 30);
    run_cand1(t);
  }

  // --- final conv ---
  k_conv<<<dim3(N_), 256, 0, stream>>>(h2, cwf, cbf, d_out, flag);
}

// Round 10
// 5764.244 us; speedup vs baseline: 5.8605x; 5.8605x over previous
//
#include <hip/hip_runtime.h>
#include <hip/hip_bf16.h>

// FP32-intermediate pipeline; R14: split-bf16 MFMA GEMM.
// R15: hoist t-invariant E-weighted merge out of the t-loop (WM buffers).
// R18: dual-n gate fallback. R19: gemmM 128x64/BK=64 stride-72.
// R20/R23: occupancy-raising attempts BOTH regressed with the same
// signature (transposed 2B scatter writes amplify through L2; at higher
// block concurrency partial lines thrash, PF loses L2 residency: R23 had
// FETCH 31MB->1.4GB, WRITE 92MB->2.2GB). Conclusion: the fallbacks are
// WRITE-contention-bound, not latency-bound. Reverted to R22 structure.
// R24: strip ALL transposed bf16 hi/lo writes from gate/cand kernels (they
// keep only coalesced fp32 n-major outputs) and produce *Th/*Tl via a new
// tiled transpose+split kernel k_trsp (64x64 LDS tile, float4 reads,
// 16-bf16 vector row writes -> zero write amplification). Same fp32 values
// feed the same f2b arithmetic -> bitwise-identical outputs.

#define B_    16
#define T_    12
#define N_    2048
#define HID_  64
#define ED_   10
#define HOR_  12
#define BH    (B_*HID_)    // 1024
#define BT    (B_*T_)      // 192

typedef __hip_bfloat16 bf16;
typedef __attribute__((ext_vector_type(8))) short short8;
typedef __attribute__((ext_vector_type(4))) float floatx4;

__device__ __forceinline__ float b2f(bf16 x){ return __bfloat162float(x); }
__device__ __forceinline__ bf16  f2b(float x){ return __float2bfloat16(x); }
__device__ __forceinline__ float bits2f(unsigned u) {
  union { float f; unsigned i; } c; c.i = u << 16; return c.f;
}
__device__ __forceinline__ float ldin(const void* p, size_t i, int isbf) {
  return isbf ? b2f(((const bf16*)p)[i]) : ((const float*)p)[i];
}
__device__ __forceinline__ void fma4(float4& a, float s, const float4& b) {
  a.x += s*b.x; a.y += s*b.y; a.z += s*b.z; a.w += s*b.w;
}

// ---------------------------------------------------------------------------
// dtype detector on E (bits 14:7 of 32-bit words: bf16 exponent vs mantissa)
// ---------------------------------------------------------------------------
__global__ void k_detect(const void* __restrict__ E, int* __restrict__ flag) {
  __shared__ int cnt;
  if (threadIdx.x == 0) cnt = 0;
  __syncthreads();
  const unsigned* w = (const unsigned*)E;
  int c = 0;
  for (int i = threadIdx.x; i < 4096; i += 256) {
    const unsigned e = (w[i] >> 7) & 0xFFu;
    if (e >= 0x6Eu && e <= 0x86u) ++c;
  }
  atomicAdd(&cnt, c);
  __syncthreads();
  if (threadIdx.x == 0) flag[0] = (cnt > 2048) ? 1 : 0;
}

// --- input casts to fp32 internal buffers ---
__global__ void k_castE(const void* __restrict__ E, float* __restrict__ Ein,
                        const int* __restrict__ flag) {
  const int i = blockIdx.x*256 + threadIdx.x;
  if (i < N_*ED_) Ein[i] = ldin(E, i, flag[0]);
}
__global__ void k_castsrc(const void* __restrict__ src, float* __restrict__ srcf,
                          const int* __restrict__ flag) {
  const int i = blockIdx.x*256 + threadIdx.x;
  if (i < B_*T_*N_) srcf[i] = ldin(src, i, flag[0]);
}
__global__ void k_castc(const void* __restrict__ cw, const void* __restrict__ cb,
                        float* __restrict__ cwf, float* __restrict__ cbf,
                        const int* __restrict__ flag) {
  const int i = blockIdx.x*256 + threadIdx.x;
  const int f = flag[0];
  if (i < HOR_*HID_) cwf[i] = ldin(cw, i, f);
  if (i < HOR_)      cbf[i] = ldin(cb, i, f);
}

// ---------------------------------------------------------------------------
// S = softmax(relu(Ein @ Ein^T), axis=1) -> fp32 row-major
// ---------------------------------------------------------------------------
__global__ __launch_bounds__(256) void k_softmax_S(const float* __restrict__ Ein,
                                                   float* __restrict__ S) {
  const int n = blockIdx.x, tid = threadIdx.x;
  __shared__ float er[ED_];
  __shared__ float red[4];
  if (tid < ED_) er[tid] = Ein[n*ED_ + tid];
  __syncthreads();
  float e[ED_];
#pragma unroll
  for (int d = 0; d < ED_; ++d) e[d] = er[d];
  float v[8];
  float mx = 0.f;
#pragma unroll
  for (int j = 0; j < 8; ++j) {
    const int m = tid + j*256;
    float dot = 0.f;
#pragma unroll
    for (int d = 0; d < ED_; ++d) dot += e[d]*Ein[m*ED_ + d];
    v[j] = fmaxf(dot, 0.f);
    mx = fmaxf(mx, v[j]);
  }
  for (int o = 32; o; o >>= 1) mx = fmaxf(mx, __shfl_xor(mx, o, 64));
  if ((tid & 63) == 0) red[tid >> 6] = mx;
  __syncthreads();
  mx = fmaxf(fmaxf(red[0], red[1]), fmaxf(red[2], red[3]));
  __syncthreads();
  float sum = 0.f;
#pragma unroll
  for (int j = 0; j < 8; ++j) { v[j] = __expf(v[j] - mx); sum += v[j]; }
  for (int o = 32; o; o >>= 1) sum += __shfl_xor(sum, o, 64);
  if ((tid & 63) == 0) red[tid >> 6] = sum;
  __syncthreads();
  sum = red[0] + red[1] + red[2] + red[3];
  const float inv = 1.f / sum;
#pragma unroll
  for (int j = 0; j < 8; ++j)
    S[(size_t)n*N_ + tid + j*256] = v[j]*inv;
}

// split fp32 -> hi/lo bf16 pair
__global__ void k_splitS(const float* __restrict__ S, bf16* __restrict__ Sh,
                         bf16* __restrict__ Sl, int n) {
  const int i = blockIdx.x*256 + threadIdx.x;
  if (i < n) {
    const float v = S[i];
    const bf16 h = f2b(v);
    Sh[i] = h;
    Sl[i] = f2b(v - b2f(h));
  }
}

// ---------------------------------------------------------------------------
// R24: tiled transpose+split: X[n][BH] fp32 -> Th[c][N_], Tl[c][N_] bf16.
// 64x64 tile via LDS; float4 coalesced reads, 16-bf16 vector row writes
// (full 64B-line coverage -> zero write amplification). Same f2b arithmetic
// as the in-kernel writes it replaces -> bitwise-identical.
// ---------------------------------------------------------------------------
__global__ __launch_bounds__(256) void k_trsp(const float* __restrict__ X,
                                              bf16* __restrict__ Th,
                                              bf16* __restrict__ Tl) {
  const int n0 = blockIdx.x * 64;
  const int c0 = blockIdx.y * 64;
  __shared__ float t[64][68];
  const int tid = threadIdx.x;
  {
    const int r = tid >> 2, q4 = (tid & 3) * 16;
    const float4* src = (const float4*)(X + (size_t)(n0 + r)*BH + c0 + q4);
#pragma unroll
    for (int u = 0; u < 4; ++u)
      *(float4*)&t[r][q4 + u*4] = src[u];
  }
  __syncthreads();
  {
    const int c = tid >> 2, sg = (tid & 3) * 16;
    bf16 hb[16], lb[16];
#pragma unroll
    for (int i = 0; i < 16; ++i) {
      const float v = t[sg + i][c];
      const bf16 h = f2b(v);
      hb[i] = h;
      lb[i] = f2b(v - b2f(h));
    }
    bf16* dh = Th + (size_t)(c0 + c)*N_ + n0 + sg;
    bf16* dl = Tl + (size_t)(c0 + c)*N_ + n0 + sg;
    *(uint4*)dh       = *(uint4*)&hb[0];
    *(uint4*)(dh + 8) = *(uint4*)&hb[8];
    *(uint4*)dl       = *(uint4*)&lb[0];
    *(uint4*)(dl + 8) = *(uint4*)&lb[8];
  }
}

// ---------------------------------------------------------------------------
// Basis weights -> PACKED d-interleaved layout, fp32 + bf16 (R13 verbatim).
// ---------------------------------------------------------------------------
template<int LAYER>
__global__ __launch_bounds__(256) void k_prepP(const void* __restrict__ Wb,
                                               float* __restrict__ PF,
                                               bf16* __restrict__ PH,
                                               int KIin, int KIP, int O,
                                               const int* __restrict__ flag) {
  const int idx = blockIdx.x*256 + threadIdx.x;
  if (idx >= ED_*O*KIP) return;
  const int d = idx / (O*KIP), rem = idx - d*O*KIP;
  const int o = rem / KIP, kp = rem - o*KIP;
  int cheb, i; bool valid;
  if (LAYER == 0) {
    cheb = (kp >= 80) ? 1 : 0;
    const int local = kp - cheb*80;
    if (local < 64)       { i = local + 1; valid = true; }
    else if (local == 64) { i = 0;         valid = true; }
    else                  { i = 0;         valid = false; }
  } else {
    cheb = kp >> 7; i = kp & 127; valid = true;
  }
  float v = 0.f;
  if (valid) v = ldin(Wb, (size_t)((d*2 + cheb)*KIin + i)*O + o, flag[0]);
  const int kg = kp >> 2, e = kp & 3;
  const size_t pi = ((size_t)(o*(KIP/4) + kg)*ED_ + d)*4 + e;
  PF[pi] = v;
  PH[pi] = f2b(v);
}

// bias vectors: outv[n][o] = sum_d Ein[n,d]*bb[d][o]
__global__ __launch_bounds__(128) void k_matb(const float* __restrict__ Ein,
                                              const void* __restrict__ bb,
                                              float* __restrict__ outv, int O,
                                              const int* __restrict__ flag) {
  const int n = blockIdx.x, tid = threadIdx.x;
  if (tid >= O) return;
  const int f = flag[0];
  float acc = 0.f;
#pragma unroll
  for (int d = 0; d < ED_; ++d) acc += Ein[n*ED_ + d]*ldin(bb, d*O + tid, f);
  outv[n*O + tid] = acc;
}

// ---------------------------------------------------------------------------
// Small 64-tile fp32 GEMM for Sx0 only (setup; XT form X[c*ldx+m]); cols=192
// ---------------------------------------------------------------------------
__global__ __launch_bounds__(256) void k_gemm64T(const float* __restrict__ S,
                                                 const float* __restrict__ X,
                                                 float* __restrict__ C,
                                                 int ldx, int ldc) {
  const int bm = blockIdx.x * 64;
  const int bc = blockIdx.y * 64;
  __shared__ float St[64][68];
  __shared__ float Xt[64][68];
  const int tid = threadIdx.x;
  const int r0 = (tid >> 4) * 4;
  const int c0 = (tid & 15) * 4;
  float acc[4][4];
#pragma unroll
  for (int i = 0; i < 4; ++i)
#pragma unroll
    for (int j = 0; j < 4; ++j) acc[i][j] = 0.f;
  for (int mk = 0; mk < N_; mk += 64) {
    {
      const int r = tid >> 2, ks = (tid & 3) * 16;
      const float* sp = S + (size_t)(bm + r)*N_ + mk + ks;
#pragma unroll
      for (int u = 0; u < 16; ++u) St[ks + u][r] = sp[u];
      const float* xp = X + (size_t)(bc + r)*ldx + mk + ks;
#pragma unroll
      for (int u = 0; u < 16; ++u) Xt[ks + u][r] = xp[u];
    }
    __syncthreads();
#pragma unroll 4
    for (int kk = 0; kk < 64; ++kk) {
      const float a0 = St[kk][r0], a1 = St[kk][r0+1],
                  a2 = St[kk][r0+2], a3 = St[kk][r0+3];
      const float b0 = Xt[kk][c0], b1 = Xt[kk][c0+1],
                  b2 = Xt[kk][c0+2], b3 = Xt[kk][c0+3];
      acc[0][0] += a0*b0; acc[0][1] += a0*b1; acc[0][2] += a0*b2; acc[0][3] += a0*b3;
      acc[1][0] += a1*b0; acc[1][1] += a1*b1; acc[1][2] += a1*b2; acc[1][3] += a1*b3;
      acc[2][0] += a2*b0; acc[2][1] += a2*b1; acc[2][2] += a2*b2; acc[2][3] += a2*b3;
      acc[3][0] += a3*b0; acc[3][1] += a3*b1; acc[3][2] += a3*b2; acc[3][3] += a3*b3;
    }
    __syncthreads();
  }
#pragma unroll
  for (int i = 0; i < 4; ++i)
#pragma unroll
    for (int j = 0; j < 4; ++j)
      C[(size_t)(bm + r0 + i)*ldc + bc + c0 + j] = acc[i][j];
}

// ---------------------------------------------------------------------------
// Split-bf16 MFMA GEMM (R19): 128x64 tile, BK=64, LDS stride 72 bf16,
// 4 waves each 64x32. Bitwise-identical accumulation order to R14.
// ---------------------------------------------------------------------------
__global__ __launch_bounds__(256) void k_gemmM(const bf16* __restrict__ Sh,
                                               const bf16* __restrict__ Sl,
                                               const bf16* __restrict__ X1h,
                                               const bf16* __restrict__ X1l,
                                               float* __restrict__ C1, int ldc1,
                                               const bf16* __restrict__ X2h,
                                               const bf16* __restrict__ X2l,
                                               float* __restrict__ C2, int ldc2,
                                               int split) {
  const int bm = blockIdx.x * 128;
  int bc = blockIdx.y * 64;
  const bf16* Xh = X1h; const bf16* Xl = X1l; float* C = C1; int ldc = ldc1;
  if (bc >= split) { Xh = X2h; Xl = X2l; C = C2; ldc = ldc2; bc -= split; }

  __shared__ __align__(16) bf16 Ah[128][72];
  __shared__ __align__(16) bf16 Al[128][72];
  __shared__ __align__(16) bf16 Bh[64][72];
  __shared__ __align__(16) bf16 Bl[64][72];
  const int tid = threadIdx.x;
  const int wave = tid >> 6, lane = tid & 63, q = lane >> 4, ln = lane & 15;
  const int wm = wave >> 1, wn = wave & 1;            // wave quadrant 2x2
  const int srow = tid >> 3, scol = (tid & 7) * 8;    // staging: 32 rows/pass

  floatx4 acc[4][2];
#pragma unroll
  for (int mt = 0; mt < 4; ++mt)
#pragma unroll
    for (int nt = 0; nt < 2; ++nt) acc[mt][nt] = (floatx4){0.f,0.f,0.f,0.f};

  for (int mk = 0; mk < N_; mk += 64) {
#pragma unroll
    for (int i = 0; i < 4; ++i) {
      const int r = i*32 + srow;
      *(uint4*)&Ah[r][scol] = *(const uint4*)(Sh + (size_t)(bm + r)*N_ + mk + scol);
      *(uint4*)&Al[r][scol] = *(const uint4*)(Sl + (size_t)(bm + r)*N_ + mk + scol);
    }
#pragma unroll
    for (int i = 0; i < 2; ++i) {
      const int r = i*32 + srow;
      *(uint4*)&Bh[r][scol] = *(const uint4*)(Xh + (size_t)(bc + r)*N_ + mk + scol);
      *(uint4*)&Bl[r][scol] = *(const uint4*)(Xl + (size_t)(bc + r)*N_ + mk + scol);
    }
    __syncthreads();
#pragma unroll
    for (int ks = 0; ks < 64; ks += 32) {
      short8 ah[4], al[4], bh[2], bl[2];
#pragma unroll
      for (int mt = 0; mt < 4; ++mt) {
        ah[mt] = *(const short8*)&Ah[wm*64 + mt*16 + ln][ks + q*8];
        al[mt] = *(const short8*)&Al[wm*64 + mt*16 + ln][ks + q*8];
      }
#pragma unroll
      for (int nt = 0; nt < 2; ++nt) {
        bh[nt] = *(const short8*)&Bh[wn*32 + nt*16 + ln][ks + q*8];
        bl[nt] = *(const short8*)&Bl[wn*32 + nt*16 + ln][ks + q*8];
      }
#pragma unroll
      for (int mt = 0; mt < 4; ++mt)
#pragma unroll
        for (int nt = 0; nt < 2; ++nt) {
          acc[mt][nt] = __builtin_amdgcn_mfma_f32_16x16x32_bf16(ah[mt], bh[nt], acc[mt][nt], 0, 0, 0);
          acc[mt][nt] = __builtin_amdgcn_mfma_f32_16x16x32_bf16(al[mt], bh[nt], acc[mt][nt], 0, 0, 0);
          acc[mt][nt] = __builtin_amdgcn_mfma_f32_16x16x32_bf16(ah[mt], bl[nt], acc[mt][nt], 0, 0, 0);
        }
    }
    __syncthreads();
  }
#pragma unroll
  for (int mt = 0; mt < 4; ++mt)
#pragma unroll
    for (int nt = 0; nt < 2; ++nt)
#pragma unroll
      for (int r = 0; r < 4; ++r)
        C[(size_t)(bm + wm*64 + mt*16 + q*4 + r)*ldc + bc + wn*32 + nt*16 + ln] =
            acc[mt][nt][r];
}

// ---------------------------------------------------------------------------
// xg builder (float4): xg[b][k], padded row stride KIPP (R13 verbatim).
// ---------------------------------------------------------------------------
template<int LAYER, int KIP, int KIPP>
__device__ __forceinline__ void build4(float (*xg)[KIPP],
                                       const float* p0, const float* p1,
                                       const float* p2, const float* p3,
                                       int n, int t, int tid) {
  constexpr int NQ = KIP/4;
  for (int idx = tid; idx < B_*NQ; idx += 256) {
    const int b = idx / NQ, k = (idx - b*NQ) * 4;
    float4 v = make_float4(0.f, 0.f, 0.f, 0.f);
    if (LAYER == 1) {
      const float* rg = (k < 64) ? p0 : (k < 128) ? p1 : (k < 192) ? p2 : p3;
      v = *(const float4*)(rg + (size_t)n*BH + b*64 + (k & 63));
    } else {
      if (k < 64)        v = *(const float4*)(p0 + (size_t)n*BH + b*64 + k);
      else if (k == 64)  v.x = p1[(size_t)(b*T_ + t)*N_ + n];
      else if (k >= 80 && k < 144)
                         v = *(const float4*)(p2 + (size_t)n*BH + b*64 + (k - 80));
      else if (k == 144) v.x = p3[(size_t)n*BT + b*T_ + t];
    }
    *(float4*)&xg[b][k] = v;
  }
}

// Packed merge (R13 verbatim)
template<int KIP>
__device__ __forceinline__ float4 merge_p(const float* __restrict__ PF,
                                          const bf16* __restrict__ PH,
                                          const float* el, int o, int kg,
                                          int isbf) {
  float4 a4 = make_float4(0.f, 0.f, 0.f, 0.f);
  const size_t gbase = (size_t)(o*(KIP/4) + kg)*(ED_*4);
  if (isbf) {
    const uint4* g = (const uint4*)(PH + gbase);
#pragma unroll
    for (int i = 0; i < 5; ++i) {
      const uint4 w = g[i];
      const float e0 = el[2*i], e1 = el[2*i + 1];
      a4.x += e0*bits2f(w.x & 0xFFFFu); a4.y += e0*bits2f(w.x >> 16);
      a4.z += e0*bits2f(w.y & 0xFFFFu); a4.w += e0*bits2f(w.y >> 16);
      a4.x += e1*bits2f(w.z & 0xFFFFu); a4.y += e1*bits2f(w.z >> 16);
      a4.z += e1*bits2f(w.w & 0xFFFFu); a4.w += e1*bits2f(w.w >> 16);
    }
  } else {
    const float4* g = (const float4*)(PF + gbase);
#pragma unroll
    for (int d = 0; d < ED_; ++d)
      fma4(a4, el[d], g[d]);
  }
  return a4;
}

// R18: dual-n merge — one basis load feeds both n's accumulators. Per-n
// accumulation order identical to merge_p (bitwise-identical results).
template<int KIP>
__device__ __forceinline__ void merge_p2(const float* __restrict__ PF,
                                         const bf16* __restrict__ PH,
                                         const float* el0, const float* el1,
                                         int o, int kg, int isbf,
                                         float4& a0, float4& a1) {
  const size_t gbase = (size_t)(o*(KIP/4) + kg)*(ED_*4);
  if (isbf) {
    const uint4* g = (const uint4*)(PH + gbase);
#pragma unroll
    for (int i = 0; i < 5; ++i) {
      const uint4 w = g[i];
      const float f0 = bits2f(w.x & 0xFFFFu), f1 = bits2f(w.x >> 16);
      const float f2 = bits2f(w.y & 0xFFFFu), f3 = bits2f(w.y >> 16);
      const float f4 = bits2f(w.z & 0xFFFFu), f5 = bits2f(w.z >> 16);
      const float f6 = bits2f(w.w & 0xFFFFu), f7 = bits2f(w.w >> 16);
      const float e00 = el0[2*i], e01 = el0[2*i + 1];
      const float e10 = el1[2*i], e11 = el1[2*i + 1];
      a0.x += e00*f0; a0.y += e00*f1; a0.z += e00*f2; a0.w += e00*f3;
      a0.x += e01*f4; a0.y += e01*f5; a0.z += e01*f6; a0.w += e01*f7;
      a1.x += e10*f0; a1.y += e10*f1; a1.z += e10*f2; a1.w += e10*f3;
      a1.x += e11*f4; a1.y += e11*f5; a1.z += e11*f6; a1.w += e11*f7;
    }
  } else {
    const float4* g = (const float4*)(PF + gbase);
#pragma unroll
    for (int d = 0; d < ED_; ++d) {
      const float4 w = g[d];
      fma4(a0, el0[d], w);
      fma4(a1, el1[d], w);
    }
  }
}

// ---------------------------------------------------------------------------
// R15: one-time merged-weight build. WM[n][o][k] (k contiguous), fp32.
// ---------------------------------------------------------------------------
template<int KIP>
__global__ __launch_bounds__(256) void k_merge(const float* __restrict__ PF,
                                               const bf16* __restrict__ PH,
                                               const float* __restrict__ Ein,
                                               float* __restrict__ WM, int O,
                                               const int* __restrict__ flag) {
  const int n = blockIdx.x;
  const int idx = blockIdx.y*256 + threadIdx.x;
  __shared__ float es[ED_];
  if (threadIdx.x < ED_) es[threadIdx.x] = Ein[n*ED_ + threadIdx.x];
  __syncthreads();
  if (idx >= O*(KIP/4)) return;
  const int o = idx / (KIP/4), kg = idx - o*(KIP/4);
  float el[ED_];
#pragma unroll
  for (int d = 0; d < ED_; ++d) el[d] = es[d];
  const float4 a4 = merge_p<KIP>(PF, PH, el, o, kg, flag[0]);
  *(float4*)&WM[((size_t)n*O + o)*KIP + kg*4] = a4;
}

// ---------------------------------------------------------------------------
// Gate (premerged, R16; R24: no transposed writes).
// ---------------------------------------------------------------------------
template<int LAYER, int KIP>
__global__ __launch_bounds__(256, 2) void k_gateWpm(const float* __restrict__ WM,
                                                    const float* __restrict__ bgv,
                                                    const float* __restrict__ p0,
                                                    const float* __restrict__ p1,
                                                    const float* __restrict__ p2,
                                                    const float* __restrict__ p3,
                                                    const float* __restrict__ hstate,
                                                    float* __restrict__ zh,
                                                    float* __restrict__ r_buf,
                                                    int t) {
  constexpr int KIPP = KIP + 4;
  constexpr int O = 128;
  const int n = blockIdx.x, tid = threadIdx.x;
  __shared__ float xg[B_][KIPP];
  __shared__ float wm[O][36];
  build4<LAYER, KIP, KIPP>(xg, p0, p1, p2, p3, n, t, tid);

  const float* WMn = WM + (size_t)n*O*KIP;
  const int b = tid >> 4, q = tid & 15;
  float acc[8];
#pragma unroll
  for (int j = 0; j < 8; ++j) acc[j] = 0.f;

  for (int k0 = 0; k0 < KIP; k0 += 32) {
#pragma unroll
    for (int i = 0; i < O*8/256; ++i) {
      const int idx = tid + i*256;
      const int o = idx >> 3, kq = idx & 7;
      *(float4*)&wm[o][kq*4] =
          *(const float4*)(WMn + (size_t)o*KIP + k0 + kq*4);
    }
    __syncthreads();   // wm ready (and xg on first iter)
#pragma unroll
    for (int kq = 0; kq < 8; ++kq) {
      const float4 xv = *(const float4*)&xg[b][k0 + kq*4];
#pragma unroll
      for (int j = 0; j < 8; ++j) {
        const float4 wv = *(const float4*)&wm[q + 16*j][kq*4];
        acc[j] += xv.x*wv.x + xv.y*wv.y + xv.z*wv.z + xv.w*wv.w;
      }
    }
    __syncthreads();
  }
#pragma unroll
  for (int j = 0; j < 8; ++j) {
    const int o = q + 16*j;
    float s = acc[j] + bgv[n*128 + o];
    s = 1.f/(1.f + __expf(-s));
    if (o < HID_) {
      const float zv = s*hstate[(size_t)n*BH + b*64 + o];
      zh[(size_t)n*BH + b*64 + o] = zv;
    } else {
      r_buf[(size_t)n*BH + b*64 + (o - HID_)] = s;
    }
  }
}

// ---------------------------------------------------------------------------
// Candidate (premerged, R16; R24: no transposed writes).
// ---------------------------------------------------------------------------
template<int LAYER, int KIP>
__global__ __launch_bounds__(256, 2) void k_candWpm(const float* __restrict__ WM,
                                                    const float* __restrict__ buv,
                                                    const float* __restrict__ p0,
                                                    const float* __restrict__ p1,
                                                    const float* __restrict__ p2,
                                                    const float* __restrict__ p3,
                                                    const float* __restrict__ r_buf,
                                                    float* __restrict__ hstate,
                                                    int t) {
  constexpr int KIPP = KIP + 4;
  constexpr int O = 64;
  const int n = blockIdx.x, tid = threadIdx.x;
  __shared__ float xg[B_][KIPP];
  __shared__ float wm[O][36];
  build4<LAYER, KIP, KIPP>(xg, p0, p1, p2, p3, n, t, tid);

  const float* WMn = WM + (size_t)n*O*KIP;
  const int b = tid >> 4, q = tid & 15;
  float acc[4];
#pragma unroll
  for (int j = 0; j < 4; ++j) acc[j] = 0.f;

  for (int k0 = 0; k0 < KIP; k0 += 32) {
#pragma unroll
    for (int i = 0; i < O*8/256; ++i) {
      const int idx = tid + i*256;
      const int o = idx >> 3, kq = idx & 7;
      *(float4*)&wm[o][kq*4] =
          *(const float4*)(WMn + (size_t)o*KIP + k0 + kq*4);
    }
    __syncthreads();
#pragma unroll
    for (int kq = 0; kq < 8; ++kq) {
      const float4 xv = *(const float4*)&xg[b][k0 + kq*4];
#pragma unroll
      for (int j = 0; j < 4; ++j) {
        const float4 wv = *(const float4*)&wm[q + 16*j][kq*4];
        acc[j] += xv.x*wv.x + xv.y*wv.y + xv.z*wv.z + xv.w*wv.w;
      }
    }
    __syncthreads();
  }
#pragma unroll
  for (int j = 0; j < 4; ++j) {
    const int o = q + 16*j;
    const float hc = tanhf(acc[j] + buv[n*64 + o]);
    const float rr = r_buf[(size_t)n*BH + b*64 + o];
    const float hold = hstate[(size_t)n*BH + b*64 + o];
    const float hn = rr*hold + (1.f - rr)*hc;
    hstate[(size_t)n*BH + b*64 + o] = hn;
  }
}

// ---------------------------------------------------------------------------
// R18 Gate fallback, TWO n per block, FULL upfront xg (R24: no transposed
// writes). Per-n arithmetic order identical -> bitwise-same.
// ---------------------------------------------------------------------------
template<int LAYER, int KIP>
__global__ __launch_bounds__(256, 2) void k_gateW2(const float* __restrict__ PF,
                                                   const bf16* __restrict__ PH,
                                                   const float* __restrict__ bgv,
                                                   const float* __restrict__ p0,
                                                   const float* __restrict__ p1,
                                                   const float* __restrict__ p2,
                                                   const float* __restrict__ p3,
                                                   const float* __restrict__ Ein,
                                                   const float* __restrict__ hstate,
                                                   float* __restrict__ zh,
                                                   float* __restrict__ r_buf,
                                                   const int* __restrict__ flag,
                                                   int t) {
  constexpr int KIPP = KIP + 4;
  constexpr int O = 128;
  const int n0 = blockIdx.x, n1 = blockIdx.x + N_/2, tid = threadIdx.x;
  __shared__ float xg[2][B_][KIPP];
  __shared__ float wm[2][O][36];
  __shared__ float es[2][ED_];
  if (tid < ED_) es[0][tid] = Ein[n0*ED_ + tid];
  if (tid >= 32 && tid < 32 + ED_) es[1][tid - 32] = Ein[n1*ED_ + (tid - 32)];
  build4<LAYER, KIP, KIPP>(xg[0], p0, p1, p2, p3, n0, t, tid);
  build4<LAYER, KIP, KIPP>(xg[1], p0, p1, p2, p3, n1, t, tid);
  __syncthreads();
  const int isbf = flag[0];
  float el0[ED_], el1[ED_];
#pragma unroll
  for (int d = 0; d < ED_; ++d) { el0[d] = es[0][d]; el1[d] = es[1][d]; }

  const int b = tid >> 4, q = tid & 15;
  float ac0[8], ac1[8];
#pragma unroll
  for (int j = 0; j < 8; ++j) { ac0[j] = 0.f; ac1[j] = 0.f; }

  for (int k0 = 0; k0 < KIP; k0 += 32) {
#pragma unroll
    for (int i = 0; i < O*8/256; ++i) {
      const int idx = tid + i*256;
      const int o = idx >> 3, kq = idx & 7;
      float4 a0 = make_float4(0.f, 0.f, 0.f, 0.f);
      float4 a1 = make_float4(0.f, 0.f, 0.f, 0.f);
      merge_p2<KIP>(PF, PH, el0, el1, o, (k0 >> 2) + kq, isbf, a0, a1);
      *(float4*)&wm[0][o][kq*4] = a0;
      *(float4*)&wm[1][o][kq*4] = a1;
    }
    __syncthreads();
#pragma unroll
    for (int kq = 0; kq < 8; ++kq) {
      const float4 xv0 = *(const float4*)&xg[0][b][k0 + kq*4];
      const float4 xv1 = *(const float4*)&xg[1][b][k0 + kq*4];
#pragma unroll
      for (int j = 0; j < 8; ++j) {
        const float4 w0 = *(const float4*)&wm[0][q + 16*j][kq*4];
        const float4 w1 = *(const float4*)&wm[1][q + 16*j][kq*4];
        ac0[j] += xv0.x*w0.x + xv0.y*w0.y + xv0.z*w0.z + xv0.w*w0.w;
        ac1[j] += xv1.x*w1.x + xv1.y*w1.y + xv1.z*w1.z + xv1.w*w1.w;
      }
    }
    __syncthreads();
  }
#pragma unroll
  for (int j = 0; j < 8; ++j) {
    const int o = q + 16*j;
    {
      float s = ac0[j] + bgv[n0*128 + o];
      s = 1.f/(1.f + __expf(-s));
      if (o < HID_) {
        zh[(size_t)n0*BH + b*64 + o] = s*hstate[(size_t)n0*BH + b*64 + o];
      } else {
        r_buf[(size_t)n0*BH + b*64 + (o - HID_)] = s;
      }
    }
    {
      float s = ac1[j] + bgv[n1*128 + o];
      s = 1.f/(1.f + __expf(-s));
      if (o < HID_) {
        zh[(size_t)n1*BH + b*64 + o] = s*hstate[(size_t)n1*BH + b*64 + o];
      } else {
        r_buf[(size_t)n1*BH + b*64 + (o - HID_)] = s;
      }
    }
  }
}

// ---------------------------------------------------------------------------
// R22 Candidate fallback, TWO n per block, FULL upfront xg (R24: no
// transposed writes). Bitwise-same per-n arithmetic.
// ---------------------------------------------------------------------------
template<int LAYER, int KIP>
__global__ __launch_bounds__(256, 2) void k_candW2f(const float* __restrict__ PF,
                                                    const bf16* __restrict__ PH,
                                                    const float* __restrict__ buv,
                                                    const float* __restrict__ p0,
                                                    const float* __restrict__ p1,
                                                    const float* __restrict__ p2,
                                                    const float* __restrict__ p3,
                                                    const float* __restrict__ Ein,
                                                    const float* __restrict__ r_buf,
                                                    float* __restrict__ hstate,
                                                    const int* __restrict__ flag,
                                                    int t) {
  constexpr int KIPP = KIP + 4;
  constexpr int O = 64;
  const int n0 = blockIdx.x, n1 = blockIdx.x + N_/2, tid = threadIdx.x;
  __shared__ float xg[2][B_][KIPP];
  __shared__ float wm[2][O][36];
  __shared__ float es[2][ED_];
  if (tid < ED_) es[0][tid] = Ein[n0*ED_ + tid];
  if (tid >= 32 && tid < 32 + ED_) es[1][tid - 32] = Ein[n1*ED_ + (tid - 32)];
  build4<LAYER, KIP, KIPP>(xg[0], p0, p1, p2, p3, n0, t, tid);
  build4<LAYER, KIP, KIPP>(xg[1], p0, p1, p2, p3, n1, t, tid);
  __syncthreads();
  const int isbf = flag[0];
  float el0[ED_], el1[ED_];
#pragma unroll
  for (int d = 0; d < ED_; ++d) { el0[d] = es[0][d]; el1[d] = es[1][d]; }

  const int b = tid >> 4, q = tid & 15;
  float ac0[4], ac1[4];
#pragma unroll
  for (int j = 0; j < 4; ++j) { ac0[j] = 0.f; ac1[j] = 0.f; }

  for (int k0 = 0; k0 < KIP; k0 += 32) {
#pragma unroll
    for (int i = 0; i < O*8/256; ++i) {
      const int idx = tid + i*256;
      const int o = idx >> 3, kq = idx & 7;
      float4 a0 = make_float4(0.f, 0.f, 0.f, 0.f);
      float4 a1 = make_float4(0.f, 0.f, 0.f, 0.f);
      merge_p2<KIP>(PF, PH, el0, el1, o, (k0 >> 2) + kq, isbf, a0, a1);
      *(float4*)&wm[0][o][kq*4] = a0;
      *(float4*)&wm[1][o][kq*4] = a1;
    }
    __syncthreads();
#pragma unroll
    for (int kq = 0; kq < 8; ++kq) {
      const float4 xv0 = *(const float4*)&xg[0][b][k0 + kq*4];
      const float4 xv1 = *(const float4*)&xg[1][b][k0 + kq*4];
#pragma unroll
      for (int j = 0; j < 4; ++j) {
        const float4 w0 = *(const float4*)&wm[0][q + 16*j][kq*4];
        const float4 w1 = *(const float4*)&wm[1][q + 16*j][kq*4];
        ac0[j] += xv0.x*w0.x + xv0.y*w0.y + xv0.z*w0.z + xv0.w*w0.w;
        ac1[j] += xv1.x*w1.x + xv1.y*w1.y + xv1.z*w1.z + xv1.w*w1.w;
      }
    }
    __syncthreads();
  }
#pragma unroll
  for (int j = 0; j < 4; ++j) {
    const int o = q + 16*j;
    {
      const float hc = tanhf(ac0[j] + buv[n0*64 + o]);
      const float rr = r_buf[(size_t)n0*BH + b*64 + o];
      const float hold = hstate[(size_t)n0*BH + b*64 + o];
      hstate[(size_t)n0*BH + b*64 + o] = rr*hold + (1.f - rr)*hc;
    }
    {
      const float hc = tanhf(ac1[j] + buv[n1*64 + o]);
      const float rr = r_buf[(size_t)n1*BH + b*64 + o];
      const float hold = hstate[(size_t)n1*BH + b*64 + o];
      hstate[(size_t)n1*BH + b*64 + o] = rr*hold + (1.f - rr)*hc;
    }
  }
}

__global__ void k_zero_f(float* __restrict__ p, int n) {
  const int i = blockIdx.x*256 + threadIdx.x;
  if (i < n) p[i] = 0.f;
}
__global__ void k_zero_out(void* __restrict__ out, int nelem,
                           const int* __restrict__ flag) {
  const int i = blockIdx.x*256 + threadIdx.x;
  if (i < nelem) {
    if (flag[0]) ((unsigned short*)out)[i] = 0;
    else         ((float*)out)[i] = 0.f;
  }
}

// out[b][hor][n] = sum_c h2[n][b*64+c]*cwf[hor][c] + cbf[hor]
__global__ __launch_bounds__(256) void k_conv(const float* __restrict__ h2,
                                              const float* __restrict__ cwf,
                                              const float* __restrict__ cbf,
                                              void* __restrict__ out,
                                              const int* __restrict__ flag) {
  const int n = blockIdx.x, tid = threadIdx.x;
  __shared__ float hs[BH];
  for (int i = tid; i < BH; i += 256) hs[i] = h2[(size_t)n*BH + i];
  __syncthreads();
  const int isbf = flag[0];
  for (int i = tid; i < B_*HOR_; i += 256) {
    const int b = i / HOR_, hor = i - b*HOR_;
    float acc = cbf[hor];
#pragma unroll
    for (int c = 0; c < HID_; ++c) acc += hs[b*HID_ + c]*cwf[hor*HID_ + c];
    const size_t oi = (size_t)(b*HOR_ + hor)*N_ + n;
    if (isbf) ((bf16*)out)[oi] = f2b(acc);
    else      ((float*)out)[oi] = acc;
  }
}

// ---------------------------------------------------------------------------
extern "C" void kernel_launch(void* const* d_in, const int* in_sizes, int n_in,
                              void* d_out, int out_size, void* d_ws, size_t ws_size,
                              hipStream_t stream) {
  const void* src = d_in[0];
  const void* E   = d_in[1];
  const void* Wg0 = d_in[2];
  const void* bg0 = d_in[3];
  const void* Wu0 = d_in[4];
  const void* bu0 = d_in[5];
  const void* Wg1 = d_in[6];
  const void* bg1 = d_in[7];
  const void* Wu1 = d_in[8];
  const void* bu1 = d_in[9];
  const void* cw  = d_in[10];
  const void* cb  = d_in[11];
  (void)in_sizes; (void)n_in;

  char* p = (char*)d_ws;
  char* ws_end = (char*)d_ws + ws_size;
  auto alloc = [&](size_t bytes) -> char* {
    char* r = p; p += (bytes + 255) & ~(size_t)255; return r;
  };
  const size_t SL = (size_t)N_*BH;
  int*   flag  = (int*)  alloc(256);
  float* Ein   = (float*)alloc((size_t)N_*ED_*4);
  float* cwf   = (float*)alloc((size_t)HOR_*HID_*4);
  float* cbf   = (float*)alloc((size_t)HOR_*4);
  float* S_f   = (float*)alloc((size_t)N_*N_*4);
  bf16*  S_hi  = (bf16*) alloc((size_t)N_*N_*2);
  bf16*  S_lo  = (bf16*) alloc((size_t)N_*N_*2);
  float* Wg0F  = (float*)alloc((size_t)ED_*128*160*4);
  float* Wu0F  = (float*)alloc((size_t)ED_*64*160*4);
  float* Wg1F  = (float*)alloc((size_t)ED_*128*256*4);
  float* Wu1F  = (float*)alloc((size_t)ED_*64*256*4);
  bf16*  Wg0H  = (bf16*) alloc((size_t)ED_*128*160*2);
  bf16*  Wu0H  = (bf16*) alloc((size_t)ED_*64*160*2);
  bf16*  Wg1H  = (bf16*) alloc((size_t)ED_*128*256*2);
  bf16*  Wu1H  = (bf16*) alloc((size_t)ED_*64*256*2);
  float* bgv0  = (float*)alloc((size_t)N_*128*4);
  float* buv0  = (float*)alloc((size_t)N_*64*4);
  float* bgv1  = (float*)alloc((size_t)N_*128*4);
  float* buv1  = (float*)alloc((size_t)N_*64*4);
  float* srcf  = (float*)alloc((size_t)BT*N_*4);
  float* Sx0   = (float*)alloc((size_t)N_*BT*4);
  float* h0    = (float*)alloc(SL*4);              // h0,h2 adjacent (one zero)
  float* h2    = (float*)alloc(SL*4);
  float* Sh_a  = (float*)alloc(SL*4);              // Sh_a,Sh_b adjacent
  float* Sh_b  = (float*)alloc(SL*4);
  float* zh    = (float*)alloc(SL*4);
  float* r_buf = (float*)alloc(SL*4);
  bf16*  zhTh  = (bf16*) alloc(SL*2);
  bf16*  zhTl  = (bf16*) alloc(SL*2);
  bf16*  h0Th  = (bf16*) alloc(SL*2);
  bf16*  h0Tl  = (bf16*) alloc(SL*2);
  bf16*  h2Th  = (bf16*) alloc(SL*2);
  bf16*  h2Tl  = (bf16*) alloc(SL*2);

  const size_t required_base = (size_t)(p - (char*)d_ws);

  // --- premerged weight tiers (optional; per-buffer fallback) ---
  float* Wu0M = (float*)alloc((size_t)N_*64*160*4);   bool pmWu0 = (p <= ws_end);
  float* Wu1M = (float*)alloc((size_t)N_*64*256*4);   bool pmWu1 = (p <= ws_end);
  float* Wg0M = (float*)alloc((size_t)N_*128*160*4);  bool pmWg0 = (p <= ws_end);
  float* Wg1M = (float*)alloc((size_t)N_*128*256*4);  bool pmWg1 = (p <= ws_end);

  auto cdiv = [](int a, int b) { return (a + b - 1) / b; };

  k_detect<<<dim3(1), 256, 0, stream>>>(E, flag);

  if (required_base > ws_size) {
    k_zero_out<<<dim3(cdiv(out_size, 256)), 256, 0, stream>>>(d_out, out_size, flag);
    return;
  }

  // --- casts + setup ---
  k_castE  <<<dim3(cdiv(N_*ED_, 256)), 256, 0, stream>>>(E, Ein, flag);
  k_castsrc<<<dim3(cdiv(BT*N_, 256)),  256, 0, stream>>>(src, srcf, flag);
  k_castc  <<<dim3(cdiv(HOR_*HID_, 256)), 256, 0, stream>>>(cw, cb, cwf, cbf, flag);
  k_prepP<0><<<dim3(cdiv(ED_*128*160, 256)), 256, 0, stream>>>(Wg0, Wg0F, Wg0H, 65, 160, 128, flag);
  k_prepP<0><<<dim3(cdiv(ED_*64*160,  256)), 256, 0, stream>>>(Wu0, Wu0F, Wu0H, 65, 160, 64, flag);
  k_prepP<1><<<dim3(cdiv(ED_*128*256, 256)), 256, 0, stream>>>(Wg1, Wg1F, Wg1H, 128, 256, 128, flag);
  k_prepP<1><<<dim3(cdiv(ED_*64*256,  256)), 256, 0, stream>>>(Wu1, Wu1F, Wu1H, 128, 256, 64, flag);
  k_matb<<<dim3(N_), 128, 0, stream>>>(Ein, bg0, bgv0, 128, flag);
  k_matb<<<dim3(N_), 128, 0, stream>>>(Ein, bu0, buv0, 64,  flag);
  k_matb<<<dim3(N_), 128, 0, stream>>>(Ein, bg1, bgv1, 128, flag);
  k_matb<<<dim3(N_), 128, 0, stream>>>(Ein, bu1, buv1, 64,  flag);
  k_softmax_S<<<dim3(N_), 256, 0, stream>>>(Ein, S_f);
  k_splitS<<<dim3(cdiv(N_*N_, 256)), 256, 0, stream>>>(S_f, S_hi, S_lo, N_*N_);

  // --- one-time merged weights (R15) ---
  if (pmWu0) k_merge<160><<<dim3(N_, 10), 256, 0, stream>>>(Wu0F, Wu0H, Ein, Wu0M, 64,  flag);
  if (pmWu1) k_merge<256><<<dim3(N_, 16), 256, 0, stream>>>(Wu1F, Wu1H, Ein, Wu1M, 64,  flag);
  if (pmWg0) k_merge<160><<<dim3(N_, 20), 256, 0, stream>>>(Wg0F, Wg0H, Ein, Wg0M, 128, flag);
  if (pmWg1) k_merge<256><<<dim3(N_, 32), 256, 0, stream>>>(Wg1F, Wg1H, Ein, Wg1M, 128, flag);

  // Sx0[n, bt] = sum_m S[n,m]*srcf[bt*N + m]  (setup, fp32 kernel)
  k_gemm64T<<<dim3(N_/64, BT/64), 256, 0, stream>>>(S_f, srcf, Sx0, N_, BT);

  // zero recurrent states + Sh_a/Sh_b (adjacent pairs; t=0 reads them)
  k_zero_f<<<dim3((int)((2*SL + 255)/256)), 256, 0, stream>>>(h0, (int)(2*SL));
  k_zero_f<<<dim3((int)((2*SL + 255)/256)), 256, 0, stream>>>(Sh_a, (int)(2*SL));

  // --- per-role launchers (premerged if the buffer fit, else per-t merge) ---
  auto run_gate0 = [&](int t) {
    if (pmWg0)
      k_gateWpm<0,160><<<dim3(N_), 256, 0, stream>>>(Wg0M, bgv0, h0, srcf, Sh_a, Sx0,
                                                     h0, zh, r_buf, t);
    else
      k_gateW2<0,160><<<dim3(N_/2), 256, 0, stream>>>(Wg0F, Wg0H, bgv0, h0, srcf, Sh_a, Sx0,
                                                      Ein, h0, zh, r_buf, flag, t);
  };
  auto run_cand0 = [&](int t) {
    if (pmWu0)
      k_candWpm<0,160><<<dim3(N_), 256, 0, stream>>>(Wu0M, buv0, zh, srcf, Sh_b, Sx0,
                                                     r_buf, h0, t);
    else
      k_candW2f<0,160><<<dim3(N_/2), 256, 0, stream>>>(Wu0F, Wu0H, buv0, zh, srcf, Sh_b, Sx0,
                                                       Ein, r_buf, h0, flag, t);
  };
  auto run_gate1 = [&](int t) {
    if (pmWg1)
      k_gateWpm<1,256><<<dim3(N_), 256, 0, stream>>>(Wg1M, bgv1, h0, h2, Sh_a, Sh_b,
                                                     h2, zh, r_buf, t);
    else
      k_gateW2<1,256><<<dim3(N_/2), 256, 0, stream>>>(Wg1F, Wg1H, bgv1, h0, h2, Sh_a, Sh_b,
                                                      Ein, h2, zh, r_buf, flag, t);
  };
  auto run_cand1 = [&](int t) {
    if (pmWu1)
      k_candWpm<1,256><<<dim3(N_), 256, 0, stream>>>(Wu1M, buv1, h0, zh, Sh_a, Sh_b,
                                                     r_buf, h2, t);
    else
      k_candW2f<1,256><<<dim3(N_/2), 256, 0, stream>>>(Wu1F, Wu1H, buv1, h0, zh, Sh_a, Sh_b,
                                                       Ein, r_buf, h2, flag, t);
  };
  auto trsp = [&](const float* X, bf16* Th, bf16* Tl) {
    k_trsp<<<dim3(N_/64, BH/64), 256, 0, stream>>>(X, Th, Tl);
  };

  // --- t = 0 (states zero: all Sh terms vanish except S@h1[0]) ---
  run_gate0(0);
  run_cand0(0);
  trsp(h0, h0Th, h0Tl);
  // Sh_a = S@h1[0]
  k_gemmM<<<dim3(N_/128, BH/64), 256, 0, stream>>>(S_hi, S_lo, h0Th, h0Tl, Sh_a, BH,
                                                   h0Th, h0Tl, Sh_a, BH, 1 << 30);
  run_gate1(0);
  run_cand1(0);
  trsp(h2, h2Th, h2Tl);

  // --- t >= 1: Sh_a from previous step's dual GEMM serves L0's S@h ---
  for (int t = 1; t < T_; ++t) {
    run_gate0(t);
    trsp(zh, zhTh, zhTl);
    // Szh0 -> Sh_b
    k_gemmM<<<dim3(N_/128, BH/64), 256, 0, stream>>>(S_hi, S_lo, zhTh, zhTl, Sh_b, BH,
                                                     zhTh, zhTl, Sh_b, BH, 1 << 30);
    run_cand0(t);
    trsp(h0, h0Th, h0Tl);
    // h0 now holds h1[:, t]; dual: Sh_a = S@h1t, Sh_b = S@h2
    k_gemmM<<<dim3(N_/128, 2*BH/64), 256, 0, stream>>>(S_hi, S_lo, h0Th, h0Tl, Sh_a, BH,
                                                       h2Th, h2Tl, Sh_b, BH, BH);
    run_gate1(t);
    trsp(zh, zhTh, zhTl);
    // Szh1 -> Sh_b
    k_gemmM<<<dim3(N_/128, BH/64), 256, 0, stream>>>(S_hi, S_lo, zhTh, zhTl, Sh_b, BH,
                                                     zhTh, zhTl, Sh_b, BH, 1 << 30);
    run_cand1(t);
    trsp(h2, h2Th, h2Tl);
  }

  // --- final conv ---
  k_conv<<<dim3(N_), 256, 0, stream>>>(h2, cwf, cbf, d_out, flag);
}